// Round 4
// baseline (281.998 us; speedup 1.0000x reference)
//
#include <hip/hip_runtime.h>
#include <math.h>

// ---------------------------------------------------------------------------
// PredictiveModule fused: one persistent kernel, 256 blocks x 1024 threads
// (1 block/CU, 16 waves/CU), 4 device-wide barriers between phases:
//   P1: p1[256][4096] = per-64-row-chunk partials of ct @ W1
//   P2: x2-slice reduce(+b1,relu) -> p2[256][4096] partials of x2 @ W2
//   P3: x3-slice reduce(+b2,relu) -> p3[128][16384] partials of x3 @ W3
//       (block pairs: 32-row k-chunk, halves of the 16384 cols)
//   P4: reduce p3 + gate/clip/sample elementwise + per-block logprob partial
//   P5: block 0: radix-select top-k (stable ties by index), write out+logprob
//
// Barriers: per-phase arrive counter + monotonic generation cell in d_ws,
// memset to 0 at the start of every launch (graph-safe, deterministic).
// Residency: 256 blocks on 256 CUs; __launch_bounds__(1024,4) caps VGPR at
// 128 so a 16-wave block always fits one CU -> no deadlock.
//
// Numerics: f64 accumulation everywhere (matvec is HBM-bound; f64 is free).
// f32 rounding mimicked only at sample = f32(am) + 0.05f*noise.
// ---------------------------------------------------------------------------

constexpr int D   = 16384;
constexpr int H   = 4096;
constexpr int NB  = 256;        // blocks
constexpr int T   = 1024;       // threads per block
constexpr int KC1 = D / NB;     // 64  rows per block, layer 1
constexpr int KC2 = H / NB;     // 16  rows per block, layer 2
constexpr int NP3 = NB / 2;     // 128 k-groups, layer 3
constexpr int KC3 = H / NP3;    // 32  rows per block-pair, layer 3

__device__ __forceinline__ double wredsum(double v) {
    #pragma unroll
    for (int o = 32; o > 0; o >>= 1) v += __shfl_down(v, o, 64);
    return v;
}

__device__ __forceinline__ void gbar(int* bar, int phase) {
    __syncthreads();
    if (threadIdx.x == 0) {
        __threadfence();
        if (atomicAdd(&bar[phase], 1) == NB - 1)
            atomicAdd(&bar[15], 1);  // generation: monotonic 0 -> 4
        while (__hip_atomic_load(&bar[15], __ATOMIC_ACQUIRE,
                                 __HIP_MEMORY_SCOPE_AGENT) < phase + 1)
            __builtin_amdgcn_s_sleep(2);
        __threadfence();
    }
    __syncthreads();
}

__global__ __launch_bounds__(T, 4) void k_fused(
    const float* __restrict__ ct,  const float* __restrict__ W1,
    const float* __restrict__ b1,  const float* __restrict__ W2,
    const float* __restrict__ b2,  const float* __restrict__ W3,
    const float* __restrict__ b3,  const float* __restrict__ qm,
    const float* __restrict__ noise, const int* __restrict__ kptr,
    int* bar, double* p1, double* p2, double* p3,
    float* samp, double* lpp, float* out)
{
    __shared__ union {
        struct { double xs[KC1]; double xred[T]; } mv;
        struct {
            int whist[16][257];
            int hist[256]; int sfx[256];
            int wsum[16]; int wcnt[4];
            unsigned int s_prefix; int s_kk;
        } tk;
    } sm;

    const int b = blockIdx.x, t = threadIdx.x;
    const int lane = t & 63, wid = t >> 6;

    // ---------------- P1: rows [b*64, +64) of W1 (K=D, N=H) ----------------
    {
        if (t < KC1) sm.mv.xs[t] = (double)ct[b * KC1 + t];
        __syncthreads();
        const float* Wp = W1 + (size_t)b * KC1 * H + t * 4;
        double a0 = 0, a1 = 0, a2 = 0, a3 = 0;
        #pragma unroll 8
        for (int kk = 0; kk < KC1; ++kk) {
            const float4 w = *reinterpret_cast<const float4*>(Wp + (size_t)kk * H);
            const double x = sm.mv.xs[kk];
            a0 += x * (double)w.x; a1 += x * (double)w.y;
            a2 += x * (double)w.z; a3 += x * (double)w.w;
        }
        double* yp = p1 + (size_t)b * H + t * 4;
        *reinterpret_cast<double2*>(yp + 0) = make_double2(a0, a1);
        *reinterpret_cast<double2*>(yp + 2) = make_double2(a2, a3);
    }
    gbar(bar, 0);

    // ---------------- P2: rows [b*16, +16) of W2 (K=H, N=H) ----------------
    {
        const int j0 = b * KC2;
        const int jl = t & (KC2 - 1), sl = t / KC2;     // 64 slices
        double s = 0;
        #pragma unroll
        for (int g = sl; g < NB; g += T / KC2)          // 4 iters
            s += p1[(size_t)g * H + j0 + jl];
        sm.mv.xred[t] = s;
        __syncthreads();
        if (t < KC2) {
            double tot = (double)b1[j0 + t];
            #pragma unroll
            for (int s2 = 0; s2 < T / KC2; ++s2) tot += sm.mv.xred[s2 * KC2 + t];
            sm.mv.xs[t] = tot > 0.0 ? tot : 0.0;        // relu
        }
        __syncthreads();
        const float* Wp = W2 + (size_t)j0 * H + t * 4;
        double a0 = 0, a1 = 0, a2 = 0, a3 = 0;
        #pragma unroll 8
        for (int kk = 0; kk < KC2; ++kk) {
            const float4 w = *reinterpret_cast<const float4*>(Wp + (size_t)kk * H);
            const double x = sm.mv.xs[kk];
            a0 += x * (double)w.x; a1 += x * (double)w.y;
            a2 += x * (double)w.z; a3 += x * (double)w.w;
        }
        double* yp = p2 + (size_t)b * H + t * 4;
        *reinterpret_cast<double2*>(yp + 0) = make_double2(a0, a1);
        *reinterpret_cast<double2*>(yp + 2) = make_double2(a2, a3);
    }
    gbar(bar, 1);

    // ------- P3: block pair p=b>>1: rows [p*32,+32) of W3 (K=H, N=D) -------
    {
        const int p = b >> 1, h = b & 1;
        const int j0 = p * KC3;
        const int jl = t & (KC3 - 1), sl = t / KC3;     // 32 slices
        double s = 0;
        #pragma unroll
        for (int g = sl; g < NB; g += T / KC3)          // 8 iters
            s += p2[(size_t)g * H + j0 + jl];
        sm.mv.xred[t] = s;
        __syncthreads();
        if (t < KC3) {
            double tot = (double)b2[j0 + t];
            #pragma unroll
            for (int s2 = 0; s2 < T / KC3; ++s2) tot += sm.mv.xred[s2 * KC3 + t];
            sm.mv.xs[t] = tot > 0.0 ? tot : 0.0;        // relu
        }
        __syncthreads();
        const int q0 = h * (D / 2) + t * 4;             // my half's first quad
        const int q1 = q0 + H;                          // +4096 cols
        double a[8] = {0, 0, 0, 0, 0, 0, 0, 0};
        #pragma unroll 4
        for (int kk = 0; kk < KC3; ++kk) {
            const double x = sm.mv.xs[kk];
            const float4 w0 = *reinterpret_cast<const float4*>(W3 + (size_t)(j0 + kk) * D + q0);
            const float4 w1 = *reinterpret_cast<const float4*>(W3 + (size_t)(j0 + kk) * D + q1);
            a[0] += x * (double)w0.x; a[1] += x * (double)w0.y;
            a[2] += x * (double)w0.z; a[3] += x * (double)w0.w;
            a[4] += x * (double)w1.x; a[5] += x * (double)w1.y;
            a[6] += x * (double)w1.z; a[7] += x * (double)w1.w;
        }
        double* y0 = p3 + (size_t)p * D + q0;
        double* y1 = p3 + (size_t)p * D + q1;
        *reinterpret_cast<double2*>(y0 + 0) = make_double2(a[0], a[1]);
        *reinterpret_cast<double2*>(y0 + 2) = make_double2(a[2], a[3]);
        *reinterpret_cast<double2*>(y1 + 0) = make_double2(a[4], a[5]);
        *reinterpret_cast<double2*>(y1 + 2) = make_double2(a[6], a[7]);
    }
    gbar(bar, 2);

    // ------------- P4: reduce p3, elementwise, logprob partials -------------
    {
        const int c0 = b * (D / NB);                    // 64 cols per block
        const int cl = t & 63, gs = t >> 6;             // 16 g-slices
        double s = 0;
        #pragma unroll
        for (int g = gs; g < NP3; g += 16)              // 8 iters
            s += p3[(size_t)g * D + c0 + cl];
        sm.mv.xred[gs * 64 + cl] = s;
        __syncthreads();
        if (t < 64) {
            const int c = c0 + t;
            double vm = (double)b3[c];
            #pragma unroll
            for (int s2 = 0; s2 < 16; ++s2) vm += sm.mv.xred[s2 * 64 + t];
            vm = vm > 100.0 ? 100.0 : (vm < -100.0 ? -100.0 : vm);
            const double z = (double)qm[c] * (double)ct[c];
            const double g = 1.0 / (1.0 + exp(-z));
            double am = g * vm;                          // influence == 1.0
            am = am > 1000.0 ? 1000.0 : (am < -1000.0 ? -1000.0 : am);
            const float amf = (float)am;
            const float sp = amf + 0.05f * noise[c];
            samp[c] = sp;
            const float df = (sp - amf) / 0.05f;
            double term = (double)df * (double)df;
            term = wredsum(term);                        // t<64 == wave 0
            if (t == 0) lpp[b] = term;
        }
    }
    gbar(bar, 3);

    // ---------------- P5: block 0 only — top-k + final write ----------------
    if (b != 0) return;

    const int k = *kptr;
    unsigned int prefix = 0;
    int kk = k;
    for (int pass = 0; pass < 4; ++pass) {
        const int shift = 24 - 8 * pass;
        const unsigned int dm = pass ? (0xffffffffu << (32 - 8 * pass)) : 0u;
        for (int i = t; i < 16 * 257; i += T) (&sm.tk.whist[0][0])[i] = 0;
        __syncthreads();
        for (int i = t; i < D; i += T) {
            const unsigned int v = __float_as_uint(samp[i]) & 0x7fffffffu;
            if ((v & dm) == prefix)
                atomicAdd(&sm.tk.whist[wid][(v >> shift) & 0xff], 1);
        }
        __syncthreads();
        if (t < 256) {
            int s = 0;
            #pragma unroll
            for (int w = 0; w < 16; ++w) s += sm.tk.whist[w][t];
            sm.tk.hist[t] = s;
            sm.tk.sfx[t] = s;
        }
        __syncthreads();
        #pragma unroll
        for (int off = 1; off < 256; off <<= 1) {
            int add = 0;
            if (t < 256 && t + off < 256) add = sm.tk.sfx[t + off];
            __syncthreads();
            if (t < 256) sm.tk.sfx[t] += add;
            __syncthreads();
        }
        const bool cond = (t < 256) && (sm.tk.sfx[t] >= kk);
        const unsigned long long m = __ballot(cond);
        if (lane == 0 && wid < 4) sm.tk.wcnt[wid] = __popcll(m);
        __syncthreads();
        if (t == 0) {
            const int bs = sm.tk.wcnt[0] + sm.tk.wcnt[1] + sm.tk.wcnt[2] + sm.tk.wcnt[3] - 1;
            sm.tk.s_kk = kk - (sm.tk.sfx[bs] - sm.tk.hist[bs]);
            sm.tk.s_prefix = prefix | ((unsigned int)bs << shift);
        }
        __syncthreads();
        prefix = sm.tk.s_prefix;
        kk = sm.tk.s_kk;
        __syncthreads();
    }
    const unsigned int vstar = prefix;
    const int need = kk;   // ties (lowest index) to keep

    // stable tie-rank: contiguous per-thread chunks preserve index order
    constexpr int PER = D / T;  // 16
    const int base = t * PER;
    float vals[PER];
    unsigned int keys[PER];
    int cnt = 0;
    #pragma unroll
    for (int j = 0; j < PER; ++j) {
        const float f = samp[base + j];
        vals[j] = f;
        keys[j] = __float_as_uint(f) & 0x7fffffffu;
        cnt += (keys[j] == vstar) ? 1 : 0;
    }
    int inc = cnt;                                       // wave inclusive scan
    #pragma unroll
    for (int o = 1; o < 64; o <<= 1) {
        const int n = __shfl_up(inc, o, 64);
        if (lane >= o) inc += n;
    }
    if (lane == 63) sm.tk.wsum[wid] = inc;
    __syncthreads();
    int woff = 0;
    for (int w = 0; w < wid; ++w) woff += sm.tk.wsum[w];
    int offset = woff + inc - cnt;                       // exclusive tie-rank
    #pragma unroll
    for (int j = 0; j < PER; ++j) {
        float o2 = 0.0f;
        if (keys[j] > vstar) {
            o2 = vals[j];
        } else if (keys[j] == vstar) {
            if (offset < need) o2 = vals[j];
            offset++;
        }
        out[base + j] = o2;
    }

    if (wid == 0) {                                      // logprob
        double s = 0;
        for (int g = lane; g < NB; g += 64) s += lpp[g];
        s = wredsum(s);
        if (lane == 0) {
            const double c = -log(0.05) - 0.5 * log(2.0 * 3.14159265358979323846);
            out[D] = (float)(-0.5 * s + (double)D * c);
        }
    }
}

extern "C" void kernel_launch(void* const* d_in, const int* in_sizes, int n_in,
                              void* d_out, int out_size, void* d_ws, size_t ws_size,
                              hipStream_t stream) {
    const float* ct    = (const float*)d_in[0];
    const float* W1    = (const float*)d_in[1];
    const float* b1    = (const float*)d_in[2];
    const float* W2    = (const float*)d_in[3];
    const float* b2    = (const float*)d_in[4];
    const float* W3    = (const float*)d_in[5];
    const float* b3    = (const float*)d_in[6];
    const float* qm    = (const float*)d_in[7];
    const float* noise = (const float*)d_in[8];
    const int*   kp    = (const int*)d_in[9];

    // ws: bar(256B) | p1[256][4096] | p2[256][4096] | p3[128][16384] | samp | lpp
    int*    bar  = (int*)d_ws;
    double* p1   = (double*)((char*)d_ws + 256);
    double* p2   = p1 + (size_t)NB * H;
    double* p3   = p2 + (size_t)NB * H;
    float*  samp = (float*)(p3 + (size_t)NP3 * D);
    double* lpp  = (double*)(samp + D);

    hipMemsetAsync(d_ws, 0, 256, stream);   // barrier state: deterministic
    k_fused<<<dim3(NB), dim3(T), 0, stream>>>(
        ct, W1, b1, W2, b2, W3, b3, qm, noise, kp,
        bar, p1, p2, p3, samp, lpp, (float*)d_out);
}